// Round 13
// baseline (238.600 us; speedup 1.0000x reference)
//
#include <hip/hip_runtime.h>
#include <hip/hip_bf16.h>

// SkipGCN: out = gcn(relu(gcn(x,W1,b1)),W2,b2) + x@Ws + bs
// N=100000, E=1600000, in=165, hid=128, out=2, fp32 in/out.
//
// R13 changes vs R12 (agg1 59.7us; model: ~2.5 serialized rounds/node at
// ~600cy each (s_load->select->gather->vmcnt0); fewer+fatter rounds):
//  - agg1: 16 edges/iteration. 4 scalar int4 col loads + TWO uint4 gathers
//    (each instr covers 8 rows: slot=lane>>3 edge-of-8, cb=lane&7 -> 16ch).
//    Slot-select via explicit 7-cndmask tree. Fold 16ch x shfl{8,16,32}.
//  - buildb: segments padded to x16 (mask 15), slab budget still < 8192.
//  - everything else identical to R12.

#define IND 165
#define HID 128
#define KP 192
#define BM 32
#define XSS2 208
#define SLAB 8192
#define MAXNB 512

typedef __attribute__((ext_vector_type(8))) short short8v;
typedef __attribute__((ext_vector_type(4))) float float4v;
typedef __attribute__((ext_vector_type(2))) float float2v;

__device__ __forceinline__ unsigned short f2bf(float f) {
    unsigned u = __float_as_uint(f);
    unsigned r = (u + 0x7FFF + ((u >> 16) & 1)) >> 16;  // RNE
    return (unsigned short)r;
}
__device__ __forceinline__ float bf2f(unsigned short s) { return __uint_as_float(((unsigned)s) << 16); }

// select element 'slot' (0..7) from two int4s via cndmask tree (no scratch)
__device__ __forceinline__ int sel8(int4 a, int4 b, int slot) {
    int t0 = (slot & 1) ? a.y : a.x;
    int t1 = (slot & 1) ? a.w : a.z;
    int t2 = (slot & 1) ? b.y : b.x;
    int t3 = (slot & 1) ? b.w : b.z;
    int u0 = (slot & 2) ? t1 : t0;
    int u1 = (slot & 2) ? t3 : t2;
    return (slot & 4) ? u1 : u0;
}

// ---- setup: w1t convert (blocks 0..95) + detect + zero bucket_len (block 96) ----
__global__ __launch_bounds__(256) void setup_kernel(const float* __restrict__ W1,
                                                    unsigned short* __restrict__ w1t,
                                                    const int* __restrict__ e32,
                                                    int* __restrict__ flag,
                                                    int* __restrict__ bucket_len, int NB) {
    int b = blockIdx.x;
    if (b < 96) {
        int t = b * 256 + threadIdx.x;
        int nn = t / KP, k = t - nn * KP;
        w1t[t] = (k < IND) ? f2bf(W1[k * HID + nn]) : (unsigned short)0;
    } else {
        __shared__ int nz;
        if (threadIdx.x == 0) nz = 0;
        __syncthreads();
        if (e32[2 * threadIdx.x + 1] != 0) atomicOr(&nz, 1);
        __syncthreads();
        if (threadIdx.x == 0) flag[0] = (nz == 0) ? 1 : 0;  // 1 => int64 layout
        for (int t = threadIdx.x; t < NB; t += 256) bucket_len[t] = 0;
    }
}

// ---- partition: edges -> per-bucket slabs of records (dstLow<<24 | src) ----
__global__ __launch_bounds__(256) void partition_kernel(const int* __restrict__ e32,
                                                        const int* __restrict__ flag,
                                                        int* __restrict__ bucket_len,
                                                        unsigned* __restrict__ slab,
                                                        int E, int NB) {
    __shared__ unsigned hist[MAXNB];
    __shared__ unsigned runbase[MAXNB];
    __shared__ unsigned cnt2[MAXNB];
    for (int t = threadIdx.x; t < NB; t += 256) { hist[t] = 0; cnt2[t] = 0; }
    __syncthreads();
    const int f = flag[0];
    const int base = blockIdx.x * 8192;
    unsigned rec[32];
    unsigned bk[32];
    #pragma unroll
    for (int j = 0; j < 32; ++j) {
        int e = base + j * 256 + threadIdx.x;
        if (e < E) {
            int src, dst;
            if (f) {
                int2 s2 = ((const int2*)e32)[e];
                int2 d2 = ((const int2*)e32)[E + e];
                src = s2.x; dst = d2.x;
            } else {
                src = e32[e];
                dst = e32[E + e];
            }
            unsigned b = (unsigned)dst >> 8;
            rec[j] = ((unsigned)(dst & 255) << 24) | (unsigned)src;
            bk[j] = b;
            atomicAdd(&hist[b], 1u);
        } else {
            bk[j] = 0xFFFFFFFFu;
            rec[j] = 0;
        }
    }
    __syncthreads();
    for (int t = threadIdx.x; t < NB; t += 256) {
        unsigned h = hist[t];
        runbase[t] = h ? (unsigned)atomicAdd(&bucket_len[t], (int)h) : 0u;
    }
    __syncthreads();
    #pragma unroll
    for (int j = 0; j < 32; ++j) {
        unsigned b = bk[j];
        if (b != 0xFFFFFFFFu) {
            unsigned p = runbase[b] + atomicAdd(&cnt2[b], 1u);
            if (p < SLAB) slab[(size_t)b * SLAB + p] = rec[j];
        }
    }
}

// ---- buildB: block per bucket -> dinv, row2(beg,end padded x16), col_src (pads=n) ----
__global__ __launch_bounds__(256) void buildb_kernel(const unsigned* __restrict__ slab,
                                                     const int* __restrict__ bucket_len,
                                                     int2* __restrict__ row2,
                                                     float* __restrict__ dinv,
                                                     int* __restrict__ col_src, int n) {
    __shared__ unsigned deg[256];
    __shared__ int qa[256], qb[256];
    __shared__ unsigned cur[256];
    const int b = blockIdx.x;
    const int t = threadIdx.x;
    const int len = min(bucket_len[b], SLAB);
    const unsigned* recs = slab + (size_t)b * SLAB;
    const int d0 = b << 8;
    const int base = b * SLAB;
    deg[t] = 0;
    __syncthreads();
    for (int i = t; i < len; i += 256) atomicAdd(&deg[recs[i] >> 24], 1u);
    __syncthreads();
    const unsigned dv = deg[t];
    const int pdv = (int)((dv + 15u) & ~15u);
    qa[t] = pdv;
    __syncthreads();
    int* s = qa; int* d = qb;
    for (int off = 1; off < 256; off <<= 1) {
        d[t] = s[t] + ((t >= off) ? s[t - off] : 0);
        __syncthreads();
        int* tmp = s; s = d; d = tmp;
    }
    int pexcl = s[t] - pdv;
    int pend = min(pexcl + pdv, SLAB);   // pathological-overflow clamp
    if (pexcl > SLAB) pexcl = SLAB;
    if (d0 + t < n) {
        dinv[d0 + t] = rsqrtf(1.0f + (float)dv);
        row2[d0 + t] = make_int2(base + pexcl, base + pend);
    }
    cur[t] = (unsigned)pexcl;
    __syncthreads();
    for (int i = t; i < len; i += 256) {
        unsigned r = recs[i];
        unsigned p = atomicAdd(&cur[r >> 24], 1u);
        if (p < (unsigned)SLAB) col_src[base + p] = (int)(r & 0xFFFFFFu);
    }
    // pad fill with sentinel n (zero row)
    for (int p = pexcl + (int)dv; p < pend; ++p)
        col_src[base + p] = n;
}

// ---- MFMA gemm1: hb8(fp8) = (x @ W1) * dinv[row], fused skip = x@Ws+bs+b2 ----
__global__ __launch_bounds__(256, 4) void gemm1_kernel(const float* __restrict__ x,
                                                       const unsigned short* __restrict__ w1t,
                                                       const float* __restrict__ Ws,
                                                       const float* __restrict__ bs,
                                                       const float* __restrict__ b2,
                                                       const float* __restrict__ dinv,
                                                       unsigned char* __restrict__ hb8,
                                                       float* __restrict__ h2p,
                                                       float* __restrict__ skip, int n) {
    __shared__ unsigned short xs[BM * XSS2];
    __shared__ float sdinv[BM];
    const int row0 = blockIdx.x * BM;
    const int tid = threadIdx.x;
    const int wave = tid >> 6, lane = tid & 63;
    const int l15 = lane & 15, lk = (lane >> 4) * 8;

    // sentinel zero row + h2p sentinel (block 0 only; disjoint region)
    if (blockIdx.x == 0) {
        if (tid < 32) ((unsigned*)(hb8 + (size_t)n * HID))[tid] = 0u;
        if (tid == 32) ((float2*)h2p)[n] = make_float2(0.f, 0.f);
    }
    if (tid < BM) sdinv[tid] = (row0 + tid < n) ? dinv[row0 + tid] : 1.f;

    short8v bfr[12];
    #pragma unroll
    for (int nt2 = 0; nt2 < 2; ++nt2)
        #pragma unroll
        for (int ks = 0; ks < 6; ++ks)
            bfr[nt2 * 6 + ks] =
                *(const short8v*)(w1t + (size_t)((2 * wave + nt2) * 16 + l15) * KP + ks * 32 + lk);

    for (int t = tid; t < BM * (XSS2 - IND); t += 256) {
        int r = t / (XSS2 - IND), k = IND + (t - r * (XSS2 - IND));
        xs[r * XSS2 + k] = 0;
    }
    {
        const int rows = min(BM, n - row0);
        const int nflt = rows * IND;
        const float2* xsrc = (const float2*)(x + (size_t)row0 * IND);
        const int nf2 = nflt >> 1;
        for (int f = tid; f < nf2; f += 256) {
            float2 v = xsrc[f];
            int e0 = 2 * f;
            int r0 = e0 / IND, k0 = e0 - r0 * IND;
            xs[r0 * XSS2 + k0] = f2bf(v.x);
            int r1 = (k0 == IND - 1) ? r0 + 1 : r0;
            int k1 = (k0 == IND - 1) ? 0 : k0 + 1;
            xs[r1 * XSS2 + k1] = f2bf(v.y);
        }
        if ((nflt & 1) && tid == 0) {
            int e = nflt - 1;
            int r = e / IND, k = e - r * IND;
            xs[r * XSS2 + k] = f2bf(x[(size_t)row0 * IND + e]);
        }
    }
    __syncthreads();

    float4v acc[2][2];
    #pragma unroll
    for (int m = 0; m < 2; ++m)
        #pragma unroll
        for (int nt2 = 0; nt2 < 2; ++nt2) acc[m][nt2] = (float4v){0.f, 0.f, 0.f, 0.f};
    #pragma unroll
    for (int m = 0; m < 2; ++m) {
        const unsigned short* arow = xs + (m * 16 + l15) * XSS2;
        #pragma unroll
        for (int ks = 0; ks < 6; ++ks) {
            short8v a = *(const short8v*)(arow + ks * 32 + lk);
            acc[m][0] = __builtin_amdgcn_mfma_f32_16x16x32_bf16(a, bfr[ks], acc[m][0], 0, 0, 0);
            acc[m][1] = __builtin_amdgcn_mfma_f32_16x16x32_bf16(a, bfr[6 + ks], acc[m][1], 0, 0, 0);
        }
    }

    // epilogue: hprime = acc * dinv[row], quantize fp8 e4m3
    #pragma unroll
    for (int m = 0; m < 2; ++m) {
        int rib0 = m * 16 + (lane >> 4) * 4;
        #pragma unroll
        for (int nt2 = 0; nt2 < 2; ++nt2) {
            int col = (2 * wave + nt2) * 16 + l15;
            #pragma unroll
            for (int r = 0; r < 4; ++r) {
                int row = row0 + rib0 + r;
                float hv = acc[m][nt2][r] * sdinv[rib0 + r];
                int pk = __builtin_amdgcn_cvt_pk_fp8_f32(hv, 0.f, 0, false);
                if (row < n) hb8[(size_t)row * HID + col] = (unsigned char)(pk & 0xFF);
            }
        }
    }

    {
        int r = tid >> 3, j = tid & 7;
        int row = row0 + r;
        float s0 = 0.f, s1 = 0.f;
        if (row < n) {
            const float2* Wsv = (const float2*)Ws;
            const unsigned short* xr = xs + r * XSS2;
            for (int k = j; k < IND; k += 8) {
                float xv = bf2f(xr[k]);
                float2 w = Wsv[k];
                s0 = fmaf(xv, w.x, s0);
                s1 = fmaf(xv, w.y, s1);
            }
        }
        s0 += __shfl_xor(s0, 1); s0 += __shfl_xor(s0, 2); s0 += __shfl_xor(s0, 4);
        s1 += __shfl_xor(s1, 1); s1 += __shfl_xor(s1, 2); s1 += __shfl_xor(s1, 4);
        if (j == 0 && row < n)
            ((float2*)skip)[row] = make_float2(s0 + bs[0] + b2[0], s1 + bs[1] + b2[1]);
    }
}

// ---- layer-1 aggregate: acc = sum hprime (+self), h1=relu(di*acc+b1),
//      h2p = (h1 @ W2) * di. Wave/node; slot=lane>>3 edge-of-8, cb=lane&7
//      loads uint4 = 16ch. 16 edges/iter: 4 scalar int4 + 2 uint4 gathers.
__global__ __launch_bounds__(256) void agg1_kernel(const unsigned char* __restrict__ hb8,
                                                   const float* __restrict__ dinv,
                                                   const int2* __restrict__ row2,
                                                   const int* __restrict__ col_src,
                                                   const float* __restrict__ b1,
                                                   const float* __restrict__ W2,
                                                   float* __restrict__ h2p, int n) {
    int wid = threadIdx.x >> 6, lane = threadIdx.x & 63;
    int i = blockIdx.x * 4 + wid;
    if (i >= n) return;
    const int slot = lane >> 3, cb = lane & 7;
    const float di = dinv[i];
    float2v a[8];   // 16 channels: 16cb .. 16cb+15
    {   // self (hprime[i]); only slot 0 contributes
        uint4 r = *(const uint4*)(hb8 + (size_t)i * 128 + cb * 16);
        float w = (slot == 0) ? 1.f : 0.f;
        float2v wv = {w, w};
        a[0] = __builtin_amdgcn_cvt_pk_f32_fp8((int)r.x, false) * wv;
        a[1] = __builtin_amdgcn_cvt_pk_f32_fp8((int)r.x, true)  * wv;
        a[2] = __builtin_amdgcn_cvt_pk_f32_fp8((int)r.y, false) * wv;
        a[3] = __builtin_amdgcn_cvt_pk_f32_fp8((int)r.y, true)  * wv;
        a[4] = __builtin_amdgcn_cvt_pk_f32_fp8((int)r.z, false) * wv;
        a[5] = __builtin_amdgcn_cvt_pk_f32_fp8((int)r.z, true)  * wv;
        a[6] = __builtin_amdgcn_cvt_pk_f32_fp8((int)r.w, false) * wv;
        a[7] = __builtin_amdgcn_cvt_pk_f32_fp8((int)r.w, true)  * wv;
    }
    const int2 be = row2[i];
    const int beg  = __builtin_amdgcn_readfirstlane(be.x);
    const int endv = __builtin_amdgcn_readfirstlane(be.y);
    for (int e = beg; e < endv; e += 16) {
        // 16 cols via scalar loads (uniform addr)
        int4 ca = *(const int4*)(col_src + e);
        int4 cbv = *(const int4*)(col_src + e + 4);
        int4 cc = *(const int4*)(col_src + e + 8);
        int4 cd = *(const int4*)(col_src + e + 12);
        int s0 = sel8(ca, cbv, slot);    // edge e + slot
        int s1 = sel8(cc, cd, slot);     // edge e + 8 + slot
        uint4 r0 = *(const uint4*)(hb8 + (size_t)s0 * 128 + cb * 16);
        uint4 r1 = *(const uint4*)(hb8 + (size_t)s1 * 128 + cb * 16);
        a[0] += __builtin_amdgcn_cvt_pk_f32_fp8((int)r0.x, false);
        a[1] += __builtin_amdgcn_cvt_pk_f32_fp8((int)r0.x, true);
        a[2] += __builtin_amdgcn_cvt_pk_f32_fp8((int)r0.y, false);
        a[3] += __builtin_amdgcn_cvt_pk_f32_fp8((int)r0.y, true);
        a[4] += __builtin_amdgcn_cvt_pk_f32_fp8((int)r0.z, false);
        a[5] += __builtin_amdgcn_cvt_pk_f32_fp8((int)r0.z, true);
        a[6] += __builtin_amdgcn_cvt_pk_f32_fp8((int)r0.w, false);
        a[7] += __builtin_amdgcn_cvt_pk_f32_fp8((int)r0.w, true);
        a[0] += __builtin_amdgcn_cvt_pk_f32_fp8((int)r1.x, false);
        a[1] += __builtin_amdgcn_cvt_pk_f32_fp8((int)r1.x, true);
        a[2] += __builtin_amdgcn_cvt_pk_f32_fp8((int)r1.y, false);
        a[3] += __builtin_amdgcn_cvt_pk_f32_fp8((int)r1.y, true);
        a[4] += __builtin_amdgcn_cvt_pk_f32_fp8((int)r1.z, false);
        a[5] += __builtin_amdgcn_cvt_pk_f32_fp8((int)r1.z, true);
        a[6] += __builtin_amdgcn_cvt_pk_f32_fp8((int)r1.w, false);
        a[7] += __builtin_amdgcn_cvt_pk_f32_fp8((int)r1.w, true);
    }
    // fold across slots (lane bits 3,4,5): 16 channels
    float f[16];
    #pragma unroll
    for (int c = 0; c < 8; ++c) { f[2 * c] = a[c].x; f[2 * c + 1] = a[c].y; }
    #pragma unroll
    for (int c = 0; c < 16; ++c) {
        f[c] += __shfl_xor(f[c], 8);
        f[c] += __shfl_xor(f[c], 16);
        f[c] += __shfl_xor(f[c], 32);
    }
    // bias + relu + W2 (channels 16cb..16cb+15)
    float p0 = 0.f, p1 = 0.f;
    #pragma unroll
    for (int q = 0; q < 4; ++q) {
        float4 bb = ((const float4*)b1)[4 * cb + q];
        float4 wa = ((const float4*)W2)[8 * cb + 2 * q];      // rows 16cb+4q, +1
        float4 wb = ((const float4*)W2)[8 * cb + 2 * q + 1];  // rows 16cb+4q+2, +3
        float v0 = fmaxf(fmaf(di, f[4 * q + 0], bb.x), 0.f);
        float v1 = fmaxf(fmaf(di, f[4 * q + 1], bb.y), 0.f);
        float v2 = fmaxf(fmaf(di, f[4 * q + 2], bb.z), 0.f);
        float v3 = fmaxf(fmaf(di, f[4 * q + 3], bb.w), 0.f);
        p0 += v0 * wa.x + v1 * wa.z + v2 * wb.x + v3 * wb.z;
        p1 += v0 * wa.y + v1 * wa.w + v2 * wb.y + v3 * wb.w;
    }
    // fold across cb (lane bits 0,1,2)
    p0 += __shfl_xor(p0, 1); p0 += __shfl_xor(p0, 2); p0 += __shfl_xor(p0, 4);
    p1 += __shfl_xor(p1, 1); p1 += __shfl_xor(p1, 2); p1 += __shfl_xor(p1, 4);
    if (lane == 0) ((float2*)h2p)[i] = make_float2(p0 * di, p1 * di);
}

// ---- layer-2 aggregate + skip: out = di*(sum h2p[src] + h2p[i]) + skip ----
__global__ __launch_bounds__(256) void agg2_kernel(const float* __restrict__ h2p,
                                                   const float* __restrict__ dinv,
                                                   const int2* __restrict__ row2,
                                                   const int* __restrict__ col_src,
                                                   const float* __restrict__ skip,
                                                   float* __restrict__ out, int n) {
    int wid = threadIdx.x >> 6, lane = threadIdx.x & 63;
    int i = blockIdx.x * 4 + wid;
    if (i >= n) return;
    float di = dinv[i];
    float a0 = 0.f, a1 = 0.f;
    const int2 be = row2[i];
    const int beg  = __builtin_amdgcn_readfirstlane(be.x);
    const int endv = __builtin_amdgcn_readfirstlane(be.y);
    for (int e = beg + lane; e < endv; e += 64) {
        int s = col_src[e];
        float2 hs = ((const float2*)h2p)[s];   // pads -> sentinel zeros
        a0 += hs.x;
        a1 += hs.y;
    }
    #pragma unroll
    for (int off = 32; off; off >>= 1) {
        a0 += __shfl_xor(a0, off);
        a1 += __shfl_xor(a1, off);
    }
    if (lane == 0) {
        float2 self = ((const float2*)h2p)[i];
        float2 sk = ((const float2*)skip)[i];
        ((float2*)out)[i] = make_float2(di * (a0 + self.x) + sk.x,
                                        di * (a1 + self.y) + sk.y);
    }
}

extern "C" void kernel_launch(void* const* d_in, const int* in_sizes, int n_in,
                              void* d_out, int out_size, void* d_ws, size_t ws_size,
                              hipStream_t stream) {
    const float* x  = (const float*)d_in[0];
    const int*   ei = (const int*)d_in[1];
    const float* W1 = (const float*)d_in[2];
    const float* b1 = (const float*)d_in[3];
    const float* W2 = (const float*)d_in[4];
    const float* b2 = (const float*)d_in[5];
    const float* Ws = (const float*)d_in[6];
    const float* bs = (const float*)d_in[7];
    float* out = (float*)d_out;

    const int n = in_sizes[0] / IND;        // 100000
    const int E = in_sizes[1] / 2;          // 1600000
    const int NB = (n + 255) >> 8;          // 391 buckets

    char* ws = (char*)d_ws;
    size_t off = 0;
    auto alloc = [&](size_t bytes) { void* p = ws + off; off += (bytes + 255) & ~(size_t)255; return p; };
    int*            flag        = (int*)alloc(256);
    int*            bucket_len  = (int*)alloc((size_t)(MAXNB + 1) * 4);
    unsigned*       slab        = (unsigned*)alloc((size_t)NB * SLAB * 4);
    int2*           row2        = (int2*)alloc((size_t)n * 8);
    float*          dinv        = (float*)alloc((size_t)n * 4);
    int*            col_src     = (int*)alloc((size_t)NB * SLAB * 4);
    unsigned char*  hb8         = (unsigned char*)alloc((size_t)(n + 1) * HID);
    float*          h2p         = (float*)alloc((size_t)(n + 1) * 2 * 4);
    float*          skip        = (float*)alloc((size_t)n * 2 * 4);
    unsigned short* w1t         = (unsigned short*)alloc((size_t)HID * KP * 2);
    (void)ws_size;

    setup_kernel<<<97, 256, 0, stream>>>(W1, w1t, ei, flag, bucket_len, NB);
    partition_kernel<<<(E + 8191) / 8192, 256, 0, stream>>>(ei, flag, bucket_len, slab, E, NB);
    buildb_kernel<<<NB, 256, 0, stream>>>(slab, bucket_len, row2, dinv, col_src, n);

    gemm1_kernel<<<(n + BM - 1) / BM, 256, 0, stream>>>(x, w1t, Ws, bs, b2, dinv, hb8, h2p, skip, n);
    agg1_kernel<<<(n + 3) / 4, 256, 0, stream>>>(hb8, dinv, row2, col_src, b1, W2, h2p, n);
    agg2_kernel<<<(n + 3) / 4, 256, 0, stream>>>(h2p, dinv, row2, col_src, skip, out, n);
}

// Round 14
// 172.132 us; speedup vs baseline: 1.3861x; 1.3861x over previous
//
#include <hip/hip_runtime.h>
#include <hip/hip_bf16.h>

// SkipGCN: out = gcn(relu(gcn(x,W1,b1)),W2,b2) + x@Ws + bs
// N=100000, E=1600000, in=165, hid=128, out=2, fp32 in/out.
//
// R14 changes vs R13 (REGRESSED 136us: uint4 gathers covering 8 rows/instr
// serialize in TA — same failure as R8; per-gather ROW COVERAGE is the
// load-bearing variable, 4 rows/instr via uint2 is the sweet spot):
//  - agg1/buildb reverted to R12 exactly (agg1 59.7us proven).
//  - DIAGNOSTIC: agg1 split into two half-range dispatches (~30us each) so
//    the invisible #2/#3 kernels (gemm1/partition, est 25-40us) surface in
//    the rocprof top-5 next round. agg1 declared at floor (~60us total):
//    pipelining (R11 null), 16-edge uint2x4 (R13/R8 regress) all exhausted.

#define IND 165
#define HID 128
#define KP 192
#define BM 32
#define XSS2 208
#define SLAB 8192
#define MAXNB 512

typedef __attribute__((ext_vector_type(8))) short short8v;
typedef __attribute__((ext_vector_type(4))) float float4v;
typedef __attribute__((ext_vector_type(2))) float float2v;

__device__ __forceinline__ unsigned short f2bf(float f) {
    unsigned u = __float_as_uint(f);
    unsigned r = (u + 0x7FFF + ((u >> 16) & 1)) >> 16;  // RNE
    return (unsigned short)r;
}
__device__ __forceinline__ float bf2f(unsigned short s) { return __uint_as_float(((unsigned)s) << 16); }

// ---- setup: w1t convert (blocks 0..95) + detect + zero bucket_len (block 96) ----
__global__ __launch_bounds__(256) void setup_kernel(const float* __restrict__ W1,
                                                    unsigned short* __restrict__ w1t,
                                                    const int* __restrict__ e32,
                                                    int* __restrict__ flag,
                                                    int* __restrict__ bucket_len, int NB) {
    int b = blockIdx.x;
    if (b < 96) {
        int t = b * 256 + threadIdx.x;
        int nn = t / KP, k = t - nn * KP;
        w1t[t] = (k < IND) ? f2bf(W1[k * HID + nn]) : (unsigned short)0;
    } else {
        __shared__ int nz;
        if (threadIdx.x == 0) nz = 0;
        __syncthreads();
        if (e32[2 * threadIdx.x + 1] != 0) atomicOr(&nz, 1);
        __syncthreads();
        if (threadIdx.x == 0) flag[0] = (nz == 0) ? 1 : 0;  // 1 => int64 layout
        for (int t = threadIdx.x; t < NB; t += 256) bucket_len[t] = 0;
    }
}

// ---- partition: edges -> per-bucket slabs of records (dstLow<<24 | src) ----
__global__ __launch_bounds__(256) void partition_kernel(const int* __restrict__ e32,
                                                        const int* __restrict__ flag,
                                                        int* __restrict__ bucket_len,
                                                        unsigned* __restrict__ slab,
                                                        int E, int NB) {
    __shared__ unsigned hist[MAXNB];
    __shared__ unsigned runbase[MAXNB];
    __shared__ unsigned cnt2[MAXNB];
    for (int t = threadIdx.x; t < NB; t += 256) { hist[t] = 0; cnt2[t] = 0; }
    __syncthreads();
    const int f = flag[0];
    const int base = blockIdx.x * 8192;
    unsigned rec[32];
    unsigned bk[32];
    #pragma unroll
    for (int j = 0; j < 32; ++j) {
        int e = base + j * 256 + threadIdx.x;
        if (e < E) {
            int src, dst;
            if (f) {
                int2 s2 = ((const int2*)e32)[e];
                int2 d2 = ((const int2*)e32)[E + e];
                src = s2.x; dst = d2.x;
            } else {
                src = e32[e];
                dst = e32[E + e];
            }
            unsigned b = (unsigned)dst >> 8;
            rec[j] = ((unsigned)(dst & 255) << 24) | (unsigned)src;
            bk[j] = b;
            atomicAdd(&hist[b], 1u);
        } else {
            bk[j] = 0xFFFFFFFFu;
            rec[j] = 0;
        }
    }
    __syncthreads();
    for (int t = threadIdx.x; t < NB; t += 256) {
        unsigned h = hist[t];
        runbase[t] = h ? (unsigned)atomicAdd(&bucket_len[t], (int)h) : 0u;
    }
    __syncthreads();
    #pragma unroll
    for (int j = 0; j < 32; ++j) {
        unsigned b = bk[j];
        if (b != 0xFFFFFFFFu) {
            unsigned p = runbase[b] + atomicAdd(&cnt2[b], 1u);
            if (p < SLAB) slab[(size_t)b * SLAB + p] = rec[j];
        }
    }
}

// ---- buildB: block per bucket -> dinv, row2(beg,end padded x8), col_src (pads=n) ----
__global__ __launch_bounds__(256) void buildb_kernel(const unsigned* __restrict__ slab,
                                                     const int* __restrict__ bucket_len,
                                                     int2* __restrict__ row2,
                                                     float* __restrict__ dinv,
                                                     int* __restrict__ col_src, int n) {
    __shared__ unsigned deg[256];
    __shared__ int qa[256], qb[256];
    __shared__ unsigned cur[256];
    const int b = blockIdx.x;
    const int t = threadIdx.x;
    const int len = min(bucket_len[b], SLAB);
    const unsigned* recs = slab + (size_t)b * SLAB;
    const int d0 = b << 8;
    const int base = b * SLAB;
    deg[t] = 0;
    __syncthreads();
    for (int i = t; i < len; i += 256) atomicAdd(&deg[recs[i] >> 24], 1u);
    __syncthreads();
    const unsigned dv = deg[t];
    const int pdv = (int)((dv + 7u) & ~7u);
    qa[t] = pdv;
    __syncthreads();
    int* s = qa; int* d = qb;
    for (int off = 1; off < 256; off <<= 1) {
        d[t] = s[t] + ((t >= off) ? s[t - off] : 0);
        __syncthreads();
        int* tmp = s; s = d; d = tmp;
    }
    int pexcl = s[t] - pdv;
    int pend = min(pexcl + pdv, SLAB);   // pathological-overflow clamp
    if (pexcl > SLAB) pexcl = SLAB;
    if (d0 + t < n) {
        dinv[d0 + t] = rsqrtf(1.0f + (float)dv);
        row2[d0 + t] = make_int2(base + pexcl, base + pend);
    }
    cur[t] = (unsigned)pexcl;
    __syncthreads();
    for (int i = t; i < len; i += 256) {
        unsigned r = recs[i];
        unsigned p = atomicAdd(&cur[r >> 24], 1u);
        if (p < (unsigned)SLAB) col_src[base + p] = (int)(r & 0xFFFFFFu);
    }
    // pad fill with sentinel n (zero row)
    for (int p = pexcl + (int)dv; p < pend; ++p)
        col_src[base + p] = n;
}

// ---- MFMA gemm1: hb8(fp8) = (x @ W1) * dinv[row], fused skip = x@Ws+bs+b2 ----
__global__ __launch_bounds__(256, 4) void gemm1_kernel(const float* __restrict__ x,
                                                       const unsigned short* __restrict__ w1t,
                                                       const float* __restrict__ Ws,
                                                       const float* __restrict__ bs,
                                                       const float* __restrict__ b2,
                                                       const float* __restrict__ dinv,
                                                       unsigned char* __restrict__ hb8,
                                                       float* __restrict__ h2p,
                                                       float* __restrict__ skip, int n) {
    __shared__ unsigned short xs[BM * XSS2];
    __shared__ float sdinv[BM];
    const int row0 = blockIdx.x * BM;
    const int tid = threadIdx.x;
    const int wave = tid >> 6, lane = tid & 63;
    const int l15 = lane & 15, lk = (lane >> 4) * 8;

    // sentinel zero row + h2p sentinel (block 0 only; disjoint region)
    if (blockIdx.x == 0) {
        if (tid < 32) ((unsigned*)(hb8 + (size_t)n * HID))[tid] = 0u;
        if (tid == 32) ((float2*)h2p)[n] = make_float2(0.f, 0.f);
    }
    if (tid < BM) sdinv[tid] = (row0 + tid < n) ? dinv[row0 + tid] : 1.f;

    short8v bfr[12];
    #pragma unroll
    for (int nt2 = 0; nt2 < 2; ++nt2)
        #pragma unroll
        for (int ks = 0; ks < 6; ++ks)
            bfr[nt2 * 6 + ks] =
                *(const short8v*)(w1t + (size_t)((2 * wave + nt2) * 16 + l15) * KP + ks * 32 + lk);

    for (int t = tid; t < BM * (XSS2 - IND); t += 256) {
        int r = t / (XSS2 - IND), k = IND + (t - r * (XSS2 - IND));
        xs[r * XSS2 + k] = 0;
    }
    {
        const int rows = min(BM, n - row0);
        const int nflt = rows * IND;
        const float2* xsrc = (const float2*)(x + (size_t)row0 * IND);
        const int nf2 = nflt >> 1;
        for (int f = tid; f < nf2; f += 256) {
            float2 v = xsrc[f];
            int e0 = 2 * f;
            int r0 = e0 / IND, k0 = e0 - r0 * IND;
            xs[r0 * XSS2 + k0] = f2bf(v.x);
            int r1 = (k0 == IND - 1) ? r0 + 1 : r0;
            int k1 = (k0 == IND - 1) ? 0 : k0 + 1;
            xs[r1 * XSS2 + k1] = f2bf(v.y);
        }
        if ((nflt & 1) && tid == 0) {
            int e = nflt - 1;
            int r = e / IND, k = e - r * IND;
            xs[r * XSS2 + k] = f2bf(x[(size_t)row0 * IND + e]);
        }
    }
    __syncthreads();

    float4v acc[2][2];
    #pragma unroll
    for (int m = 0; m < 2; ++m)
        #pragma unroll
        for (int nt2 = 0; nt2 < 2; ++nt2) acc[m][nt2] = (float4v){0.f, 0.f, 0.f, 0.f};
    #pragma unroll
    for (int m = 0; m < 2; ++m) {
        const unsigned short* arow = xs + (m * 16 + l15) * XSS2;
        #pragma unroll
        for (int ks = 0; ks < 6; ++ks) {
            short8v a = *(const short8v*)(arow + ks * 32 + lk);
            acc[m][0] = __builtin_amdgcn_mfma_f32_16x16x32_bf16(a, bfr[ks], acc[m][0], 0, 0, 0);
            acc[m][1] = __builtin_amdgcn_mfma_f32_16x16x32_bf16(a, bfr[6 + ks], acc[m][1], 0, 0, 0);
        }
    }

    // epilogue: hprime = acc * dinv[row], quantize fp8 e4m3
    #pragma unroll
    for (int m = 0; m < 2; ++m) {
        int rib0 = m * 16 + (lane >> 4) * 4;
        #pragma unroll
        for (int nt2 = 0; nt2 < 2; ++nt2) {
            int col = (2 * wave + nt2) * 16 + l15;
            #pragma unroll
            for (int r = 0; r < 4; ++r) {
                int row = row0 + rib0 + r;
                float hv = acc[m][nt2][r] * sdinv[rib0 + r];
                int pk = __builtin_amdgcn_cvt_pk_fp8_f32(hv, 0.f, 0, false);
                if (row < n) hb8[(size_t)row * HID + col] = (unsigned char)(pk & 0xFF);
            }
        }
    }

    {
        int r = tid >> 3, j = tid & 7;
        int row = row0 + r;
        float s0 = 0.f, s1 = 0.f;
        if (row < n) {
            const float2* Wsv = (const float2*)Ws;
            const unsigned short* xr = xs + r * XSS2;
            for (int k = j; k < IND; k += 8) {
                float xv = bf2f(xr[k]);
                float2 w = Wsv[k];
                s0 = fmaf(xv, w.x, s0);
                s1 = fmaf(xv, w.y, s1);
            }
        }
        s0 += __shfl_xor(s0, 1); s0 += __shfl_xor(s0, 2); s0 += __shfl_xor(s0, 4);
        s1 += __shfl_xor(s1, 1); s1 += __shfl_xor(s1, 2); s1 += __shfl_xor(s1, 4);
        if (j == 0 && row < n)
            ((float2*)skip)[row] = make_float2(s0 + bs[0] + b2[0], s1 + bs[1] + b2[1]);
    }
}

// ---- layer-1 aggregate (R12 structure, half-range dispatch) ----
// acc = sum hprime (+self), h1=relu(di*acc+b1), h2p=(h1@W2)*di.
// Wave/node; slot=lane>>4, cl=lane&15 (uint2=8ch). Scalar col loads.
__global__ __launch_bounds__(256) void agg1_kernel(const unsigned char* __restrict__ hb8,
                                                   const float* __restrict__ dinv,
                                                   const int2* __restrict__ row2,
                                                   const int* __restrict__ col_src,
                                                   const float* __restrict__ b1,
                                                   const float* __restrict__ W2,
                                                   float* __restrict__ h2p,
                                                   int i0, int iend) {
    int wid = threadIdx.x >> 6, lane = threadIdx.x & 63;
    int i = i0 + blockIdx.x * 4 + wid;
    if (i >= iend) return;
    const int slot = lane >> 4, cl = lane & 15;
    const float di = dinv[i];
    float2v a0, a1, a2, a3;
    {   // self (hprime[i]); only slot 0 contributes
        uint2 r = *(const uint2*)(hb8 + (size_t)i * 128 + cl * 8);
        float w = (slot == 0) ? 1.f : 0.f;
        float2v wv = {w, w};
        a0 = __builtin_amdgcn_cvt_pk_f32_fp8((int)r.x, false) * wv;
        a1 = __builtin_amdgcn_cvt_pk_f32_fp8((int)r.x, true)  * wv;
        a2 = __builtin_amdgcn_cvt_pk_f32_fp8((int)r.y, false) * wv;
        a3 = __builtin_amdgcn_cvt_pk_f32_fp8((int)r.y, true)  * wv;
    }
    const int2 be = row2[i];
    const int beg  = __builtin_amdgcn_readfirstlane(be.x);
    const int endv = __builtin_amdgcn_readfirstlane(be.y);
    for (int e = beg; e < endv; e += 8) {
        int4 c0 = *(const int4*)(col_src + e);       // uniform addr -> s_load
        int4 c1 = *(const int4*)(col_src + e + 4);
        int sx0 = (slot & 1) ? c0.y : c0.x;
        int sy0 = (slot & 1) ? c0.w : c0.z;
        int s0  = (slot & 2) ? sy0 : sx0;
        int sx1 = (slot & 1) ? c1.y : c1.x;
        int sy1 = (slot & 1) ? c1.w : c1.z;
        int s1  = (slot & 2) ? sy1 : sx1;
        uint2 r0 = *(const uint2*)(hb8 + (size_t)s0 * 128 + cl * 8);
        uint2 r1 = *(const uint2*)(hb8 + (size_t)s1 * 128 + cl * 8);
        a0 += __builtin_amdgcn_cvt_pk_f32_fp8((int)r0.x, false);
        a1 += __builtin_amdgcn_cvt_pk_f32_fp8((int)r0.x, true);
        a2 += __builtin_amdgcn_cvt_pk_f32_fp8((int)r0.y, false);
        a3 += __builtin_amdgcn_cvt_pk_f32_fp8((int)r0.y, true);
        a0 += __builtin_amdgcn_cvt_pk_f32_fp8((int)r1.x, false);
        a1 += __builtin_amdgcn_cvt_pk_f32_fp8((int)r1.x, true);
        a2 += __builtin_amdgcn_cvt_pk_f32_fp8((int)r1.y, false);
        a3 += __builtin_amdgcn_cvt_pk_f32_fp8((int)r1.y, true);
    }
    float a[8] = {a0.x, a0.y, a1.x, a1.y, a2.x, a2.y, a3.x, a3.y};
    // fold slots (lane bits 4,5)
    #pragma unroll
    for (int c = 0; c < 8; ++c) {
        a[c] += __shfl_xor(a[c], 16);
        a[c] += __shfl_xor(a[c], 32);
    }
    // bias + relu + W2 (channels 8cl..8cl+7)
    float4 bA = ((const float4*)b1)[2 * cl];
    float4 bB = ((const float4*)b1)[2 * cl + 1];
    float v0 = fmaxf(fmaf(di, a[0], bA.x), 0.f);
    float v1 = fmaxf(fmaf(di, a[1], bA.y), 0.f);
    float v2 = fmaxf(fmaf(di, a[2], bA.z), 0.f);
    float v3 = fmaxf(fmaf(di, a[3], bA.w), 0.f);
    float v4 = fmaxf(fmaf(di, a[4], bB.x), 0.f);
    float v5 = fmaxf(fmaf(di, a[5], bB.y), 0.f);
    float v6 = fmaxf(fmaf(di, a[6], bB.z), 0.f);
    float v7 = fmaxf(fmaf(di, a[7], bB.w), 0.f);
    float4 wA = ((const float4*)W2)[4 * cl];      // rows 8cl,8cl+1
    float4 wB = ((const float4*)W2)[4 * cl + 1];  // rows 8cl+2,8cl+3
    float4 wC = ((const float4*)W2)[4 * cl + 2];
    float4 wD = ((const float4*)W2)[4 * cl + 3];
    float p0 = v0 * wA.x + v1 * wA.z + v2 * wB.x + v3 * wB.z
             + v4 * wC.x + v5 * wC.z + v6 * wD.x + v7 * wD.z;
    float p1 = v0 * wA.y + v1 * wA.w + v2 * wB.y + v3 * wB.w
             + v4 * wC.y + v5 * wC.w + v6 * wD.y + v7 * wD.w;
    p0 += __shfl_xor(p0, 1); p0 += __shfl_xor(p0, 2);
    p0 += __shfl_xor(p0, 4); p0 += __shfl_xor(p0, 8);
    p1 += __shfl_xor(p1, 1); p1 += __shfl_xor(p1, 2);
    p1 += __shfl_xor(p1, 4); p1 += __shfl_xor(p1, 8);
    if (lane == 0) ((float2*)h2p)[i] = make_float2(p0 * di, p1 * di);
}

// ---- layer-2 aggregate + skip: out = di*(sum h2p[src] + h2p[i]) + skip ----
__global__ __launch_bounds__(256) void agg2_kernel(const float* __restrict__ h2p,
                                                   const float* __restrict__ dinv,
                                                   const int2* __restrict__ row2,
                                                   const int* __restrict__ col_src,
                                                   const float* __restrict__ skip,
                                                   float* __restrict__ out, int n) {
    int wid = threadIdx.x >> 6, lane = threadIdx.x & 63;
    int i = blockIdx.x * 4 + wid;
    if (i >= n) return;
    float di = dinv[i];
    float a0 = 0.f, a1 = 0.f;
    const int2 be = row2[i];
    const int beg  = __builtin_amdgcn_readfirstlane(be.x);
    const int endv = __builtin_amdgcn_readfirstlane(be.y);
    for (int e = beg + lane; e < endv; e += 64) {
        int s = col_src[e];
        float2 hs = ((const float2*)h2p)[s];   // pads -> sentinel zeros
        a0 += hs.x;
        a1 += hs.y;
    }
    #pragma unroll
    for (int off = 32; off; off >>= 1) {
        a0 += __shfl_xor(a0, off);
        a1 += __shfl_xor(a1, off);
    }
    if (lane == 0) {
        float2 self = ((const float2*)h2p)[i];
        float2 sk = ((const float2*)skip)[i];
        ((float2*)out)[i] = make_float2(di * (a0 + self.x) + sk.x,
                                        di * (a1 + self.y) + sk.y);
    }
}

extern "C" void kernel_launch(void* const* d_in, const int* in_sizes, int n_in,
                              void* d_out, int out_size, void* d_ws, size_t ws_size,
                              hipStream_t stream) {
    const float* x  = (const float*)d_in[0];
    const int*   ei = (const int*)d_in[1];
    const float* W1 = (const float*)d_in[2];
    const float* b1 = (const float*)d_in[3];
    const float* W2 = (const float*)d_in[4];
    const float* b2 = (const float*)d_in[5];
    const float* Ws = (const float*)d_in[6];
    const float* bs = (const float*)d_in[7];
    float* out = (float*)d_out;

    const int n = in_sizes[0] / IND;        // 100000
    const int E = in_sizes[1] / 2;          // 1600000
    const int NB = (n + 255) >> 8;          // 391 buckets

    char* ws = (char*)d_ws;
    size_t off = 0;
    auto alloc = [&](size_t bytes) { void* p = ws + off; off += (bytes + 255) & ~(size_t)255; return p; };
    int*            flag        = (int*)alloc(256);
    int*            bucket_len  = (int*)alloc((size_t)(MAXNB + 1) * 4);
    unsigned*       slab        = (unsigned*)alloc((size_t)NB * SLAB * 4);
    int2*           row2        = (int2*)alloc((size_t)n * 8);
    float*          dinv        = (float*)alloc((size_t)n * 4);
    int*            col_src     = (int*)alloc((size_t)NB * SLAB * 4);
    unsigned char*  hb8         = (unsigned char*)alloc((size_t)(n + 1) * HID);
    float*          h2p         = (float*)alloc((size_t)(n + 1) * 2 * 4);
    float*          skip        = (float*)alloc((size_t)n * 2 * 4);
    unsigned short* w1t         = (unsigned short*)alloc((size_t)HID * KP * 2);
    (void)ws_size;

    setup_kernel<<<97, 256, 0, stream>>>(W1, w1t, ei, flag, bucket_len, NB);
    partition_kernel<<<(E + 8191) / 8192, 256, 0, stream>>>(ei, flag, bucket_len, slab, E, NB);
    buildb_kernel<<<NB, 256, 0, stream>>>(slab, bucket_len, row2, dinv, col_src, n);

    gemm1_kernel<<<(n + BM - 1) / BM, 256, 0, stream>>>(x, w1t, Ws, bs, b2, dinv, hb8, h2p, skip, n);

    const int half = (n + 1) / 2;
    agg1_kernel<<<(half + 3) / 4, 256, 0, stream>>>(hb8, dinv, row2, col_src, b1, W2, h2p, 0, half);
    agg1_kernel<<<(n - half + 3) / 4, 256, 0, stream>>>(hb8, dinv, row2, col_src, b1, W2, h2p, half, n);

    agg2_kernel<<<(n + 3) / 4, 256, 0, stream>>>(h2p, dinv, row2, col_src, skip, out, n);
}

// Round 15
// 170.252 us; speedup vs baseline: 1.4015x; 1.0110x over previous
//
#include <hip/hip_runtime.h>
#include <hip/hip_bf16.h>

// SkipGCN: out = gcn(relu(gcn(x,W1,b1)),W2,b2) + x@Ws + bs
// N=100000, E=1600000, in=165, hid=128, out=2, fp32 in/out.
//
// R15 changes vs R14 (gemm1 surfaced at 49us: MfmaUtil 3.5%, warm replay
// 49us @ 13.6MB HBM -> ~47us of staging/skip serial latency chains):
//  - gemm1 staging: fixed-trip (n%BM==0 -> 2640 float2/block) 10+1 unrolled,
//    ALL loads issued to registers first (11 in flight), then LDS writes.
//    L3 latency paid once per block instead of 11x. Masked fallback kept.
//  - Ws staged to LDS: skip tail's 21 global loads -> LDS reads.
//  - gemm1 split into 2 half-grid dispatches (diagnostic: surfaces
//    partition/agg2 in next top-5). Sentinel pinned to dispatch 0.
//  - agg1 (R12 structure, still split 2x), agg2, CSR build unchanged.

#define IND 165
#define HID 128
#define KP 192
#define BM 32
#define XSS2 208
#define SLAB 8192
#define MAXNB 512

typedef __attribute__((ext_vector_type(8))) short short8v;
typedef __attribute__((ext_vector_type(4))) float float4v;
typedef __attribute__((ext_vector_type(2))) float float2v;

__device__ __forceinline__ unsigned short f2bf(float f) {
    unsigned u = __float_as_uint(f);
    unsigned r = (u + 0x7FFF + ((u >> 16) & 1)) >> 16;  // RNE
    return (unsigned short)r;
}
__device__ __forceinline__ float bf2f(unsigned short s) { return __uint_as_float(((unsigned)s) << 16); }

// ---- setup: w1t convert (blocks 0..95) + detect + zero bucket_len (block 96) ----
__global__ __launch_bounds__(256) void setup_kernel(const float* __restrict__ W1,
                                                    unsigned short* __restrict__ w1t,
                                                    const int* __restrict__ e32,
                                                    int* __restrict__ flag,
                                                    int* __restrict__ bucket_len, int NB) {
    int b = blockIdx.x;
    if (b < 96) {
        int t = b * 256 + threadIdx.x;
        int nn = t / KP, k = t - nn * KP;
        w1t[t] = (k < IND) ? f2bf(W1[k * HID + nn]) : (unsigned short)0;
    } else {
        __shared__ int nz;
        if (threadIdx.x == 0) nz = 0;
        __syncthreads();
        if (e32[2 * threadIdx.x + 1] != 0) atomicOr(&nz, 1);
        __syncthreads();
        if (threadIdx.x == 0) flag[0] = (nz == 0) ? 1 : 0;  // 1 => int64 layout
        for (int t = threadIdx.x; t < NB; t += 256) bucket_len[t] = 0;
    }
}

// ---- partition: edges -> per-bucket slabs of records (dstLow<<24 | src) ----
__global__ __launch_bounds__(256) void partition_kernel(const int* __restrict__ e32,
                                                        const int* __restrict__ flag,
                                                        int* __restrict__ bucket_len,
                                                        unsigned* __restrict__ slab,
                                                        int E, int NB) {
    __shared__ unsigned hist[MAXNB];
    __shared__ unsigned runbase[MAXNB];
    __shared__ unsigned cnt2[MAXNB];
    for (int t = threadIdx.x; t < NB; t += 256) { hist[t] = 0; cnt2[t] = 0; }
    __syncthreads();
    const int f = flag[0];
    const int base = blockIdx.x * 8192;
    unsigned rec[32];
    unsigned bk[32];
    #pragma unroll
    for (int j = 0; j < 32; ++j) {
        int e = base + j * 256 + threadIdx.x;
        if (e < E) {
            int src, dst;
            if (f) {
                int2 s2 = ((const int2*)e32)[e];
                int2 d2 = ((const int2*)e32)[E + e];
                src = s2.x; dst = d2.x;
            } else {
                src = e32[e];
                dst = e32[E + e];
            }
            unsigned b = (unsigned)dst >> 8;
            rec[j] = ((unsigned)(dst & 255) << 24) | (unsigned)src;
            bk[j] = b;
            atomicAdd(&hist[b], 1u);
        } else {
            bk[j] = 0xFFFFFFFFu;
            rec[j] = 0;
        }
    }
    __syncthreads();
    for (int t = threadIdx.x; t < NB; t += 256) {
        unsigned h = hist[t];
        runbase[t] = h ? (unsigned)atomicAdd(&bucket_len[t], (int)h) : 0u;
    }
    __syncthreads();
    #pragma unroll
    for (int j = 0; j < 32; ++j) {
        unsigned b = bk[j];
        if (b != 0xFFFFFFFFu) {
            unsigned p = runbase[b] + atomicAdd(&cnt2[b], 1u);
            if (p < SLAB) slab[(size_t)b * SLAB + p] = rec[j];
        }
    }
}

// ---- buildB: block per bucket -> dinv, row2(beg,end padded x8), col_src (pads=n) ----
__global__ __launch_bounds__(256) void buildb_kernel(const unsigned* __restrict__ slab,
                                                     const int* __restrict__ bucket_len,
                                                     int2* __restrict__ row2,
                                                     float* __restrict__ dinv,
                                                     int* __restrict__ col_src, int n) {
    __shared__ unsigned deg[256];
    __shared__ int qa[256], qb[256];
    __shared__ unsigned cur[256];
    const int b = blockIdx.x;
    const int t = threadIdx.x;
    const int len = min(bucket_len[b], SLAB);
    const unsigned* recs = slab + (size_t)b * SLAB;
    const int d0 = b << 8;
    const int base = b * SLAB;
    deg[t] = 0;
    __syncthreads();
    for (int i = t; i < len; i += 256) atomicAdd(&deg[recs[i] >> 24], 1u);
    __syncthreads();
    const unsigned dv = deg[t];
    const int pdv = (int)((dv + 7u) & ~7u);
    qa[t] = pdv;
    __syncthreads();
    int* s = qa; int* d = qb;
    for (int off = 1; off < 256; off <<= 1) {
        d[t] = s[t] + ((t >= off) ? s[t - off] : 0);
        __syncthreads();
        int* tmp = s; s = d; d = tmp;
    }
    int pexcl = s[t] - pdv;
    int pend = min(pexcl + pdv, SLAB);   // pathological-overflow clamp
    if (pexcl > SLAB) pexcl = SLAB;
    if (d0 + t < n) {
        dinv[d0 + t] = rsqrtf(1.0f + (float)dv);
        row2[d0 + t] = make_int2(base + pexcl, base + pend);
    }
    cur[t] = (unsigned)pexcl;
    __syncthreads();
    for (int i = t; i < len; i += 256) {
        unsigned r = recs[i];
        unsigned p = atomicAdd(&cur[r >> 24], 1u);
        if (p < (unsigned)SLAB) col_src[base + p] = (int)(r & 0xFFFFFFu);
    }
    // pad fill with sentinel n (zero row)
    for (int p = pexcl + (int)dv; p < pend; ++p)
        col_src[base + p] = n;
}

// ---- MFMA gemm1: hb8(fp8) = (x @ W1) * dinv[row], fused skip = x@Ws+bs+b2 ----
// bstart: grid offset (dispatch split); sentinel written only when bstart==0.
__global__ __launch_bounds__(256, 4) void gemm1_kernel(const float* __restrict__ x,
                                                       const unsigned short* __restrict__ w1t,
                                                       const float* __restrict__ Ws,
                                                       const float* __restrict__ bs,
                                                       const float* __restrict__ b2,
                                                       const float* __restrict__ dinv,
                                                       unsigned char* __restrict__ hb8,
                                                       float* __restrict__ h2p,
                                                       float* __restrict__ skip,
                                                       int n, int bstart) {
    __shared__ unsigned short xs[BM * XSS2];
    __shared__ float sdinv[BM];
    __shared__ float2 wss[IND];
    const int blk = bstart + blockIdx.x;
    const int row0 = blk * BM;
    const int tid = threadIdx.x;
    const int wave = tid >> 6, lane = tid & 63;
    const int l15 = lane & 15, lk = (lane >> 4) * 8;

    // sentinel zero row + h2p sentinel (global block 0 only)
    if (bstart == 0 && blockIdx.x == 0) {
        if (tid < 32) ((unsigned*)(hb8 + (size_t)n * HID))[tid] = 0u;
        if (tid == 32) ((float2*)h2p)[n] = make_float2(0.f, 0.f);
    }
    if (tid < BM) sdinv[tid] = (row0 + tid < n) ? dinv[row0 + tid] : 1.f;
    if (tid < IND) wss[tid] = ((const float2*)Ws)[tid];

    short8v bfr[12];
    #pragma unroll
    for (int nt2 = 0; nt2 < 2; ++nt2)
        #pragma unroll
        for (int ks = 0; ks < 6; ++ks)
            bfr[nt2 * 6 + ks] =
                *(const short8v*)(w1t + (size_t)((2 * wave + nt2) * 16 + l15) * KP + ks * 32 + lk);

    // zero-pad k in [165,208)
    for (int t = tid; t < BM * (XSS2 - IND); t += 256) {
        int r = t / (XSS2 - IND), k = IND + (t - r * (XSS2 - IND));
        xs[r * XSS2 + k] = 0;
    }
    // stage x: fast path (full 32 rows) = fixed 10+1 trips, loads batched
    {
        const int rows = min(BM, n - row0);
        const float2* xsrc = (const float2*)(x + (size_t)row0 * IND);
        if (rows == BM) {
            // nflt = 5280, nf2 = 2640 = 10*256 + 80
            float2 v[11];
            #pragma unroll
            for (int j = 0; j < 10; ++j) v[j] = xsrc[j * 256 + tid];
            if (tid < 80) v[10] = xsrc[2560 + tid];
            #pragma unroll
            for (int j = 0; j < 11; ++j) {
                if (j == 10 && tid >= 80) break;
                int e0 = 2 * (j * 256 + tid);
                int r0 = e0 / IND, k0 = e0 - r0 * IND;
                xs[r0 * XSS2 + k0] = f2bf(v[j].x);
                int r1 = (k0 == IND - 1) ? r0 + 1 : r0;
                int k1 = (k0 == IND - 1) ? 0 : k0 + 1;
                xs[r1 * XSS2 + k1] = f2bf(v[j].y);
            }
        } else {
            const int nflt = rows * IND;
            const int nf2 = nflt >> 1;
            for (int f = tid; f < nf2; f += 256) {
                float2 v = xsrc[f];
                int e0 = 2 * f;
                int r0 = e0 / IND, k0 = e0 - r0 * IND;
                xs[r0 * XSS2 + k0] = f2bf(v.x);
                int r1 = (k0 == IND - 1) ? r0 + 1 : r0;
                int k1 = (k0 == IND - 1) ? 0 : k0 + 1;
                xs[r1 * XSS2 + k1] = f2bf(v.y);
            }
            if ((nflt & 1) && tid == 0) {
                int e = nflt - 1;
                int r = e / IND, k = e - r * IND;
                xs[r * XSS2 + k] = f2bf(x[(size_t)row0 * IND + e]);
            }
        }
    }
    __syncthreads();

    float4v acc[2][2];
    #pragma unroll
    for (int m = 0; m < 2; ++m)
        #pragma unroll
        for (int nt2 = 0; nt2 < 2; ++nt2) acc[m][nt2] = (float4v){0.f, 0.f, 0.f, 0.f};
    #pragma unroll
    for (int m = 0; m < 2; ++m) {
        const unsigned short* arow = xs + (m * 16 + l15) * XSS2;
        #pragma unroll
        for (int ks = 0; ks < 6; ++ks) {
            short8v a = *(const short8v*)(arow + ks * 32 + lk);
            acc[m][0] = __builtin_amdgcn_mfma_f32_16x16x32_bf16(a, bfr[ks], acc[m][0], 0, 0, 0);
            acc[m][1] = __builtin_amdgcn_mfma_f32_16x16x32_bf16(a, bfr[6 + ks], acc[m][1], 0, 0, 0);
        }
    }

    // epilogue: hprime = acc * dinv[row], quantize fp8 e4m3
    #pragma unroll
    for (int m = 0; m < 2; ++m) {
        int rib0 = m * 16 + (lane >> 4) * 4;
        #pragma unroll
        for (int nt2 = 0; nt2 < 2; ++nt2) {
            int col = (2 * wave + nt2) * 16 + l15;
            #pragma unroll
            for (int r = 0; r < 4; ++r) {
                int row = row0 + rib0 + r;
                float hv = acc[m][nt2][r] * sdinv[rib0 + r];
                int pk = __builtin_amdgcn_cvt_pk_fp8_f32(hv, 0.f, 0, false);
                if (row < n) hb8[(size_t)row * HID + col] = (unsigned char)(pk & 0xFF);
            }
        }
    }

    // skip from LDS bf16 x and LDS Ws: 8 threads per row
    {
        int r = tid >> 3, j = tid & 7;
        int row = row0 + r;
        float s0 = 0.f, s1 = 0.f;
        if (row < n) {
            const unsigned short* xr = xs + r * XSS2;
            for (int k = j; k < IND; k += 8) {
                float xv = bf2f(xr[k]);
                float2 w = wss[k];
                s0 = fmaf(xv, w.x, s0);
                s1 = fmaf(xv, w.y, s1);
            }
        }
        s0 += __shfl_xor(s0, 1); s0 += __shfl_xor(s0, 2); s0 += __shfl_xor(s0, 4);
        s1 += __shfl_xor(s1, 1); s1 += __shfl_xor(s1, 2); s1 += __shfl_xor(s1, 4);
        if (j == 0 && row < n)
            ((float2*)skip)[row] = make_float2(s0 + bs[0] + b2[0], s1 + bs[1] + b2[1]);
    }
}

// ---- layer-1 aggregate (R12 structure, half-range dispatch) ----
__global__ __launch_bounds__(256) void agg1_kernel(const unsigned char* __restrict__ hb8,
                                                   const float* __restrict__ dinv,
                                                   const int2* __restrict__ row2,
                                                   const int* __restrict__ col_src,
                                                   const float* __restrict__ b1,
                                                   const float* __restrict__ W2,
                                                   float* __restrict__ h2p,
                                                   int i0, int iend) {
    int wid = threadIdx.x >> 6, lane = threadIdx.x & 63;
    int i = i0 + blockIdx.x * 4 + wid;
    if (i >= iend) return;
    const int slot = lane >> 4, cl = lane & 15;
    const float di = dinv[i];
    float2v a0, a1, a2, a3;
    {   // self (hprime[i]); only slot 0 contributes
        uint2 r = *(const uint2*)(hb8 + (size_t)i * 128 + cl * 8);
        float w = (slot == 0) ? 1.f : 0.f;
        float2v wv = {w, w};
        a0 = __builtin_amdgcn_cvt_pk_f32_fp8((int)r.x, false) * wv;
        a1 = __builtin_amdgcn_cvt_pk_f32_fp8((int)r.x, true)  * wv;
        a2 = __builtin_amdgcn_cvt_pk_f32_fp8((int)r.y, false) * wv;
        a3 = __builtin_amdgcn_cvt_pk_f32_fp8((int)r.y, true)  * wv;
    }
    const int2 be = row2[i];
    const int beg  = __builtin_amdgcn_readfirstlane(be.x);
    const int endv = __builtin_amdgcn_readfirstlane(be.y);
    for (int e = beg; e < endv; e += 8) {
        int4 c0 = *(const int4*)(col_src + e);       // uniform addr -> s_load
        int4 c1 = *(const int4*)(col_src + e + 4);
        int sx0 = (slot & 1) ? c0.y : c0.x;
        int sy0 = (slot & 1) ? c0.w : c0.z;
        int s0  = (slot & 2) ? sy0 : sx0;
        int sx1 = (slot & 1) ? c1.y : c1.x;
        int sy1 = (slot & 1) ? c1.w : c1.z;
        int s1  = (slot & 2) ? sy1 : sx1;
        uint2 r0 = *(const uint2*)(hb8 + (size_t)s0 * 128 + cl * 8);
        uint2 r1 = *(const uint2*)(hb8 + (size_t)s1 * 128 + cl * 8);
        a0 += __builtin_amdgcn_cvt_pk_f32_fp8((int)r0.x, false);
        a1 += __builtin_amdgcn_cvt_pk_f32_fp8((int)r0.x, true);
        a2 += __builtin_amdgcn_cvt_pk_f32_fp8((int)r0.y, false);
        a3 += __builtin_amdgcn_cvt_pk_f32_fp8((int)r0.y, true);
        a0 += __builtin_amdgcn_cvt_pk_f32_fp8((int)r1.x, false);
        a1 += __builtin_amdgcn_cvt_pk_f32_fp8((int)r1.x, true);
        a2 += __builtin_amdgcn_cvt_pk_f32_fp8((int)r1.y, false);
        a3 += __builtin_amdgcn_cvt_pk_f32_fp8((int)r1.y, true);
    }
    float a[8] = {a0.x, a0.y, a1.x, a1.y, a2.x, a2.y, a3.x, a3.y};
    // fold slots (lane bits 4,5)
    #pragma unroll
    for (int c = 0; c < 8; ++c) {
        a[c] += __shfl_xor(a[c], 16);
        a[c] += __shfl_xor(a[c], 32);
    }
    // bias + relu + W2 (channels 8cl..8cl+7)
    float4 bA = ((const float4*)b1)[2 * cl];
    float4 bB = ((const float4*)b1)[2 * cl + 1];
    float v0 = fmaxf(fmaf(di, a[0], bA.x), 0.f);
    float v1 = fmaxf(fmaf(di, a[1], bA.y), 0.f);
    float v2 = fmaxf(fmaf(di, a[2], bA.z), 0.f);
    float v3 = fmaxf(fmaf(di, a[3], bA.w), 0.f);
    float v4 = fmaxf(fmaf(di, a[4], bB.x), 0.f);
    float v5 = fmaxf(fmaf(di, a[5], bB.y), 0.f);
    float v6 = fmaxf(fmaf(di, a[6], bB.z), 0.f);
    float v7 = fmaxf(fmaf(di, a[7], bB.w), 0.f);
    float4 wA = ((const float4*)W2)[4 * cl];
    float4 wB = ((const float4*)W2)[4 * cl + 1];
    float4 wC = ((const float4*)W2)[4 * cl + 2];
    float4 wD = ((const float4*)W2)[4 * cl + 3];
    float p0 = v0 * wA.x + v1 * wA.z + v2 * wB.x + v3 * wB.z
             + v4 * wC.x + v5 * wC.z + v6 * wD.x + v7 * wD.z;
    float p1 = v0 * wA.y + v1 * wA.w + v2 * wB.y + v3 * wB.w
             + v4 * wC.y + v5 * wC.w + v6 * wD.y + v7 * wD.w;
    p0 += __shfl_xor(p0, 1); p0 += __shfl_xor(p0, 2);
    p0 += __shfl_xor(p0, 4); p0 += __shfl_xor(p0, 8);
    p1 += __shfl_xor(p1, 1); p1 += __shfl_xor(p1, 2);
    p1 += __shfl_xor(p1, 4); p1 += __shfl_xor(p1, 8);
    if (lane == 0) ((float2*)h2p)[i] = make_float2(p0 * di, p1 * di);
}

// ---- layer-2 aggregate + skip: out = di*(sum h2p[src] + h2p[i]) + skip ----
__global__ __launch_bounds__(256) void agg2_kernel(const float* __restrict__ h2p,
                                                   const float* __restrict__ dinv,
                                                   const int2* __restrict__ row2,
                                                   const int* __restrict__ col_src,
                                                   const float* __restrict__ skip,
                                                   float* __restrict__ out, int n) {
    int wid = threadIdx.x >> 6, lane = threadIdx.x & 63;
    int i = blockIdx.x * 4 + wid;
    if (i >= n) return;
    float di = dinv[i];
    float a0 = 0.f, a1 = 0.f;
    const int2 be = row2[i];
    const int beg  = __builtin_amdgcn_readfirstlane(be.x);
    const int endv = __builtin_amdgcn_readfirstlane(be.y);
    for (int e = beg + lane; e < endv; e += 64) {
        int s = col_src[e];
        float2 hs = ((const float2*)h2p)[s];   // pads -> sentinel zeros
        a0 += hs.x;
        a1 += hs.y;
    }
    #pragma unroll
    for (int off = 32; off; off >>= 1) {
        a0 += __shfl_xor(a0, off);
        a1 += __shfl_xor(a1, off);
    }
    if (lane == 0) {
        float2 self = ((const float2*)h2p)[i];
        float2 sk = ((const float2*)skip)[i];
        ((float2*)out)[i] = make_float2(di * (a0 + self.x) + sk.x,
                                        di * (a1 + self.y) + sk.y);
    }
}

extern "C" void kernel_launch(void* const* d_in, const int* in_sizes, int n_in,
                              void* d_out, int out_size, void* d_ws, size_t ws_size,
                              hipStream_t stream) {
    const float* x  = (const float*)d_in[0];
    const int*   ei = (const int*)d_in[1];
    const float* W1 = (const float*)d_in[2];
    const float* b1 = (const float*)d_in[3];
    const float* W2 = (const float*)d_in[4];
    const float* b2 = (const float*)d_in[5];
    const float* Ws = (const float*)d_in[6];
    const float* bs = (const float*)d_in[7];
    float* out = (float*)d_out;

    const int n = in_sizes[0] / IND;        // 100000
    const int E = in_sizes[1] / 2;          // 1600000
    const int NB = (n + 255) >> 8;          // 391 buckets

    char* ws = (char*)d_ws;
    size_t off = 0;
    auto alloc = [&](size_t bytes) { void* p = ws + off; off += (bytes + 255) & ~(size_t)255; return p; };
    int*            flag        = (int*)alloc(256);
    int*            bucket_len  = (int*)alloc((size_t)(MAXNB + 1) * 4);
    unsigned*       slab        = (unsigned*)alloc((size_t)NB * SLAB * 4);
    int2*           row2        = (int2*)alloc((size_t)n * 8);
    float*          dinv        = (float*)alloc((size_t)n * 4);
    int*            col_src     = (int*)alloc((size_t)NB * SLAB * 4);
    unsigned char*  hb8         = (unsigned char*)alloc((size_t)(n + 1) * HID);
    float*          h2p         = (float*)alloc((size_t)(n + 1) * 2 * 4);
    float*          skip        = (float*)alloc((size_t)n * 2 * 4);
    unsigned short* w1t         = (unsigned short*)alloc((size_t)HID * KP * 2);
    (void)ws_size;

    setup_kernel<<<97, 256, 0, stream>>>(W1, w1t, ei, flag, bucket_len, NB);
    partition_kernel<<<(E + 8191) / 8192, 256, 0, stream>>>(ei, flag, bucket_len, slab, E, NB);
    buildb_kernel<<<NB, 256, 0, stream>>>(slab, bucket_len, row2, dinv, col_src, n);

    const int nblk = (n + BM - 1) / BM;     // 3125
    const int gh = (nblk + 1) / 2;          // 1563
    gemm1_kernel<<<gh, 256, 0, stream>>>(x, w1t, Ws, bs, b2, dinv, hb8, h2p, skip, n, 0);
    gemm1_kernel<<<nblk - gh, 256, 0, stream>>>(x, w1t, Ws, bs, b2, dinv, hb8, h2p, skip, n, gh);

    const int half = (n + 1) / 2;
    agg1_kernel<<<(half + 3) / 4, 256, 0, stream>>>(hb8, dinv, row2, col_src, b1, W2, h2p, 0, half);
    agg1_kernel<<<(n - half + 3) / 4, 256, 0, stream>>>(hb8, dinv, row2, col_src, b1, W2, h2p, half, n);

    agg2_kernel<<<(n + 3) / 4, 256, 0, stream>>>(h2p, dinv, row2, col_src, skip, out, n);
}

// Round 16
// 146.170 us; speedup vs baseline: 1.6323x; 1.1648x over previous
//
#include <hip/hip_runtime.h>
#include <hip/hip_bf16.h>

// SkipGCN: out = gcn(relu(gcn(x,W1,b1)),W2,b2) + x@Ws + bs
// N=100000, E=1600000, in=165, hid=128, out=2, fp32 in/out.
//
// R16 changes vs R15 (top-5 flooded by 40us harness fills; splits <40us
// invisible; gemm1 fixed-trip staging was ~null):
//  - gemm1 and agg1 merged back to single dispatches (split cost ~6.5us;
//    at ~49/~60us they rank above the fills -> counters visible again).
//  - agg2 quarter-wave-per-node: 16 lanes per node (deg~16.7), 4 nodes per
//    wave -> 4x lane utilization, 4x fewer waves.
//  - gemm1 internals kept from R15 (fixed-trip staging + LDS Ws).

#define IND 165
#define HID 128
#define KP 192
#define BM 32
#define XSS2 208
#define SLAB 8192
#define MAXNB 512

typedef __attribute__((ext_vector_type(8))) short short8v;
typedef __attribute__((ext_vector_type(4))) float float4v;
typedef __attribute__((ext_vector_type(2))) float float2v;

__device__ __forceinline__ unsigned short f2bf(float f) {
    unsigned u = __float_as_uint(f);
    unsigned r = (u + 0x7FFF + ((u >> 16) & 1)) >> 16;  // RNE
    return (unsigned short)r;
}
__device__ __forceinline__ float bf2f(unsigned short s) { return __uint_as_float(((unsigned)s) << 16); }

// ---- setup: w1t convert (blocks 0..95) + detect + zero bucket_len (block 96) ----
__global__ __launch_bounds__(256) void setup_kernel(const float* __restrict__ W1,
                                                    unsigned short* __restrict__ w1t,
                                                    const int* __restrict__ e32,
                                                    int* __restrict__ flag,
                                                    int* __restrict__ bucket_len, int NB) {
    int b = blockIdx.x;
    if (b < 96) {
        int t = b * 256 + threadIdx.x;
        int nn = t / KP, k = t - nn * KP;
        w1t[t] = (k < IND) ? f2bf(W1[k * HID + nn]) : (unsigned short)0;
    } else {
        __shared__ int nz;
        if (threadIdx.x == 0) nz = 0;
        __syncthreads();
        if (e32[2 * threadIdx.x + 1] != 0) atomicOr(&nz, 1);
        __syncthreads();
        if (threadIdx.x == 0) flag[0] = (nz == 0) ? 1 : 0;  // 1 => int64 layout
        for (int t = threadIdx.x; t < NB; t += 256) bucket_len[t] = 0;
    }
}

// ---- partition: edges -> per-bucket slabs of records (dstLow<<24 | src) ----
__global__ __launch_bounds__(256) void partition_kernel(const int* __restrict__ e32,
                                                        const int* __restrict__ flag,
                                                        int* __restrict__ bucket_len,
                                                        unsigned* __restrict__ slab,
                                                        int E, int NB) {
    __shared__ unsigned hist[MAXNB];
    __shared__ unsigned runbase[MAXNB];
    __shared__ unsigned cnt2[MAXNB];
    for (int t = threadIdx.x; t < NB; t += 256) { hist[t] = 0; cnt2[t] = 0; }
    __syncthreads();
    const int f = flag[0];
    const int base = blockIdx.x * 8192;
    unsigned rec[32];
    unsigned bk[32];
    #pragma unroll
    for (int j = 0; j < 32; ++j) {
        int e = base + j * 256 + threadIdx.x;
        if (e < E) {
            int src, dst;
            if (f) {
                int2 s2 = ((const int2*)e32)[e];
                int2 d2 = ((const int2*)e32)[E + e];
                src = s2.x; dst = d2.x;
            } else {
                src = e32[e];
                dst = e32[E + e];
            }
            unsigned b = (unsigned)dst >> 8;
            rec[j] = ((unsigned)(dst & 255) << 24) | (unsigned)src;
            bk[j] = b;
            atomicAdd(&hist[b], 1u);
        } else {
            bk[j] = 0xFFFFFFFFu;
            rec[j] = 0;
        }
    }
    __syncthreads();
    for (int t = threadIdx.x; t < NB; t += 256) {
        unsigned h = hist[t];
        runbase[t] = h ? (unsigned)atomicAdd(&bucket_len[t], (int)h) : 0u;
    }
    __syncthreads();
    #pragma unroll
    for (int j = 0; j < 32; ++j) {
        unsigned b = bk[j];
        if (b != 0xFFFFFFFFu) {
            unsigned p = runbase[b] + atomicAdd(&cnt2[b], 1u);
            if (p < SLAB) slab[(size_t)b * SLAB + p] = rec[j];
        }
    }
}

// ---- buildB: block per bucket -> dinv, row2(beg,end padded x8), col_src (pads=n) ----
__global__ __launch_bounds__(256) void buildb_kernel(const unsigned* __restrict__ slab,
                                                     const int* __restrict__ bucket_len,
                                                     int2* __restrict__ row2,
                                                     float* __restrict__ dinv,
                                                     int* __restrict__ col_src, int n) {
    __shared__ unsigned deg[256];
    __shared__ int qa[256], qb[256];
    __shared__ unsigned cur[256];
    const int b = blockIdx.x;
    const int t = threadIdx.x;
    const int len = min(bucket_len[b], SLAB);
    const unsigned* recs = slab + (size_t)b * SLAB;
    const int d0 = b << 8;
    const int base = b * SLAB;
    deg[t] = 0;
    __syncthreads();
    for (int i = t; i < len; i += 256) atomicAdd(&deg[recs[i] >> 24], 1u);
    __syncthreads();
    const unsigned dv = deg[t];
    const int pdv = (int)((dv + 7u) & ~7u);
    qa[t] = pdv;
    __syncthreads();
    int* s = qa; int* d = qb;
    for (int off = 1; off < 256; off <<= 1) {
        d[t] = s[t] + ((t >= off) ? s[t - off] : 0);
        __syncthreads();
        int* tmp = s; s = d; d = tmp;
    }
    int pexcl = s[t] - pdv;
    int pend = min(pexcl + pdv, SLAB);   // pathological-overflow clamp
    if (pexcl > SLAB) pexcl = SLAB;
    if (d0 + t < n) {
        dinv[d0 + t] = rsqrtf(1.0f + (float)dv);
        row2[d0 + t] = make_int2(base + pexcl, base + pend);
    }
    cur[t] = (unsigned)pexcl;
    __syncthreads();
    for (int i = t; i < len; i += 256) {
        unsigned r = recs[i];
        unsigned p = atomicAdd(&cur[r >> 24], 1u);
        if (p < (unsigned)SLAB) col_src[base + p] = (int)(r & 0xFFFFFFu);
    }
    // pad fill with sentinel n (zero row)
    for (int p = pexcl + (int)dv; p < pend; ++p)
        col_src[base + p] = n;
}

// ---- MFMA gemm1: hb8(fp8) = (x @ W1) * dinv[row], fused skip = x@Ws+bs+b2 ----
__global__ __launch_bounds__(256, 4) void gemm1_kernel(const float* __restrict__ x,
                                                       const unsigned short* __restrict__ w1t,
                                                       const float* __restrict__ Ws,
                                                       const float* __restrict__ bs,
                                                       const float* __restrict__ b2,
                                                       const float* __restrict__ dinv,
                                                       unsigned char* __restrict__ hb8,
                                                       float* __restrict__ h2p,
                                                       float* __restrict__ skip, int n) {
    __shared__ unsigned short xs[BM * XSS2];
    __shared__ float sdinv[BM];
    __shared__ float2 wss[IND];
    const int row0 = blockIdx.x * BM;
    const int tid = threadIdx.x;
    const int wave = tid >> 6, lane = tid & 63;
    const int l15 = lane & 15, lk = (lane >> 4) * 8;

    // sentinel zero row + h2p sentinel (block 0 only)
    if (blockIdx.x == 0) {
        if (tid < 32) ((unsigned*)(hb8 + (size_t)n * HID))[tid] = 0u;
        if (tid == 32) ((float2*)h2p)[n] = make_float2(0.f, 0.f);
    }
    if (tid < BM) sdinv[tid] = (row0 + tid < n) ? dinv[row0 + tid] : 1.f;
    if (tid < IND) wss[tid] = ((const float2*)Ws)[tid];

    short8v bfr[12];
    #pragma unroll
    for (int nt2 = 0; nt2 < 2; ++nt2)
        #pragma unroll
        for (int ks = 0; ks < 6; ++ks)
            bfr[nt2 * 6 + ks] =
                *(const short8v*)(w1t + (size_t)((2 * wave + nt2) * 16 + l15) * KP + ks * 32 + lk);

    // zero-pad k in [165,208)
    for (int t = tid; t < BM * (XSS2 - IND); t += 256) {
        int r = t / (XSS2 - IND), k = IND + (t - r * (XSS2 - IND));
        xs[r * XSS2 + k] = 0;
    }
    // stage x: fast path (full 32 rows) = fixed 10+1 trips, loads batched
    {
        const int rows = min(BM, n - row0);
        const float2* xsrc = (const float2*)(x + (size_t)row0 * IND);
        if (rows == BM) {
            float2 v[11];
            #pragma unroll
            for (int j = 0; j < 10; ++j) v[j] = xsrc[j * 256 + tid];
            if (tid < 80) v[10] = xsrc[2560 + tid];
            #pragma unroll
            for (int j = 0; j < 11; ++j) {
                if (j == 10 && tid >= 80) break;
                int e0 = 2 * (j * 256 + tid);
                int r0 = e0 / IND, k0 = e0 - r0 * IND;
                xs[r0 * XSS2 + k0] = f2bf(v[j].x);
                int r1 = (k0 == IND - 1) ? r0 + 1 : r0;
                int k1 = (k0 == IND - 1) ? 0 : k0 + 1;
                xs[r1 * XSS2 + k1] = f2bf(v[j].y);
            }
        } else {
            const int nflt = rows * IND;
            const int nf2 = nflt >> 1;
            for (int f = tid; f < nf2; f += 256) {
                float2 v = xsrc[f];
                int e0 = 2 * f;
                int r0 = e0 / IND, k0 = e0 - r0 * IND;
                xs[r0 * XSS2 + k0] = f2bf(v.x);
                int r1 = (k0 == IND - 1) ? r0 + 1 : r0;
                int k1 = (k0 == IND - 1) ? 0 : k0 + 1;
                xs[r1 * XSS2 + k1] = f2bf(v.y);
            }
            if ((nflt & 1) && tid == 0) {
                int e = nflt - 1;
                int r = e / IND, k = e - r * IND;
                xs[r * XSS2 + k] = f2bf(x[(size_t)row0 * IND + e]);
            }
        }
    }
    __syncthreads();

    float4v acc[2][2];
    #pragma unroll
    for (int m = 0; m < 2; ++m)
        #pragma unroll
        for (int nt2 = 0; nt2 < 2; ++nt2) acc[m][nt2] = (float4v){0.f, 0.f, 0.f, 0.f};
    #pragma unroll
    for (int m = 0; m < 2; ++m) {
        const unsigned short* arow = xs + (m * 16 + l15) * XSS2;
        #pragma unroll
        for (int ks = 0; ks < 6; ++ks) {
            short8v a = *(const short8v*)(arow + ks * 32 + lk);
            acc[m][0] = __builtin_amdgcn_mfma_f32_16x16x32_bf16(a, bfr[ks], acc[m][0], 0, 0, 0);
            acc[m][1] = __builtin_amdgcn_mfma_f32_16x16x32_bf16(a, bfr[6 + ks], acc[m][1], 0, 0, 0);
        }
    }

    // epilogue: hprime = acc * dinv[row], quantize fp8 e4m3
    #pragma unroll
    for (int m = 0; m < 2; ++m) {
        int rib0 = m * 16 + (lane >> 4) * 4;
        #pragma unroll
        for (int nt2 = 0; nt2 < 2; ++nt2) {
            int col = (2 * wave + nt2) * 16 + l15;
            #pragma unroll
            for (int r = 0; r < 4; ++r) {
                int row = row0 + rib0 + r;
                float hv = acc[m][nt2][r] * sdinv[rib0 + r];
                int pk = __builtin_amdgcn_cvt_pk_fp8_f32(hv, 0.f, 0, false);
                if (row < n) hb8[(size_t)row * HID + col] = (unsigned char)(pk & 0xFF);
            }
        }
    }

    // skip from LDS bf16 x and LDS Ws: 8 threads per row
    {
        int r = tid >> 3, j = tid & 7;
        int row = row0 + r;
        float s0 = 0.f, s1 = 0.f;
        if (row < n) {
            const unsigned short* xr = xs + r * XSS2;
            for (int k = j; k < IND; k += 8) {
                float xv = bf2f(xr[k]);
                float2 w = wss[k];
                s0 = fmaf(xv, w.x, s0);
                s1 = fmaf(xv, w.y, s1);
            }
        }
        s0 += __shfl_xor(s0, 1); s0 += __shfl_xor(s0, 2); s0 += __shfl_xor(s0, 4);
        s1 += __shfl_xor(s1, 1); s1 += __shfl_xor(s1, 2); s1 += __shfl_xor(s1, 4);
        if (j == 0 && row < n)
            ((float2*)skip)[row] = make_float2(s0 + bs[0] + b2[0], s1 + bs[1] + b2[1]);
    }
}

// ---- layer-1 aggregate (R12 structure, single dispatch) ----
__global__ __launch_bounds__(256) void agg1_kernel(const unsigned char* __restrict__ hb8,
                                                   const float* __restrict__ dinv,
                                                   const int2* __restrict__ row2,
                                                   const int* __restrict__ col_src,
                                                   const float* __restrict__ b1,
                                                   const float* __restrict__ W2,
                                                   float* __restrict__ h2p, int n) {
    int wid = threadIdx.x >> 6, lane = threadIdx.x & 63;
    int i = blockIdx.x * 4 + wid;
    if (i >= n) return;
    const int slot = lane >> 4, cl = lane & 15;
    const float di = dinv[i];
    float2v a0, a1, a2, a3;
    {   // self (hprime[i]); only slot 0 contributes
        uint2 r = *(const uint2*)(hb8 + (size_t)i * 128 + cl * 8);
        float w = (slot == 0) ? 1.f : 0.f;
        float2v wv = {w, w};
        a0 = __builtin_amdgcn_cvt_pk_f32_fp8((int)r.x, false) * wv;
        a1 = __builtin_amdgcn_cvt_pk_f32_fp8((int)r.x, true)  * wv;
        a2 = __builtin_amdgcn_cvt_pk_f32_fp8((int)r.y, false) * wv;
        a3 = __builtin_amdgcn_cvt_pk_f32_fp8((int)r.y, true)  * wv;
    }
    const int2 be = row2[i];
    const int beg  = __builtin_amdgcn_readfirstlane(be.x);
    const int endv = __builtin_amdgcn_readfirstlane(be.y);
    for (int e = beg; e < endv; e += 8) {
        int4 c0 = *(const int4*)(col_src + e);       // uniform addr -> s_load
        int4 c1 = *(const int4*)(col_src + e + 4);
        int sx0 = (slot & 1) ? c0.y : c0.x;
        int sy0 = (slot & 1) ? c0.w : c0.z;
        int s0  = (slot & 2) ? sy0 : sx0;
        int sx1 = (slot & 1) ? c1.y : c1.x;
        int sy1 = (slot & 1) ? c1.w : c1.z;
        int s1  = (slot & 2) ? sy1 : sx1;
        uint2 r0 = *(const uint2*)(hb8 + (size_t)s0 * 128 + cl * 8);
        uint2 r1 = *(const uint2*)(hb8 + (size_t)s1 * 128 + cl * 8);
        a0 += __builtin_amdgcn_cvt_pk_f32_fp8((int)r0.x, false);
        a1 += __builtin_amdgcn_cvt_pk_f32_fp8((int)r0.x, true);
        a2 += __builtin_amdgcn_cvt_pk_f32_fp8((int)r0.y, false);
        a3 += __builtin_amdgcn_cvt_pk_f32_fp8((int)r0.y, true);
        a0 += __builtin_amdgcn_cvt_pk_f32_fp8((int)r1.x, false);
        a1 += __builtin_amdgcn_cvt_pk_f32_fp8((int)r1.x, true);
        a2 += __builtin_amdgcn_cvt_pk_f32_fp8((int)r1.y, false);
        a3 += __builtin_amdgcn_cvt_pk_f32_fp8((int)r1.y, true);
    }
    float a[8] = {a0.x, a0.y, a1.x, a1.y, a2.x, a2.y, a3.x, a3.y};
    // fold slots (lane bits 4,5)
    #pragma unroll
    for (int c = 0; c < 8; ++c) {
        a[c] += __shfl_xor(a[c], 16);
        a[c] += __shfl_xor(a[c], 32);
    }
    // bias + relu + W2 (channels 8cl..8cl+7)
    float4 bA = ((const float4*)b1)[2 * cl];
    float4 bB = ((const float4*)b1)[2 * cl + 1];
    float v0 = fmaxf(fmaf(di, a[0], bA.x), 0.f);
    float v1 = fmaxf(fmaf(di, a[1], bA.y), 0.f);
    float v2 = fmaxf(fmaf(di, a[2], bA.z), 0.f);
    float v3 = fmaxf(fmaf(di, a[3], bA.w), 0.f);
    float v4 = fmaxf(fmaf(di, a[4], bB.x), 0.f);
    float v5 = fmaxf(fmaf(di, a[5], bB.y), 0.f);
    float v6 = fmaxf(fmaf(di, a[6], bB.z), 0.f);
    float v7 = fmaxf(fmaf(di, a[7], bB.w), 0.f);
    float4 wA = ((const float4*)W2)[4 * cl];
    float4 wB = ((const float4*)W2)[4 * cl + 1];
    float4 wC = ((const float4*)W2)[4 * cl + 2];
    float4 wD = ((const float4*)W2)[4 * cl + 3];
    float p0 = v0 * wA.x + v1 * wA.z + v2 * wB.x + v3 * wB.z
             + v4 * wC.x + v5 * wC.z + v6 * wD.x + v7 * wD.z;
    float p1 = v0 * wA.y + v1 * wA.w + v2 * wB.y + v3 * wB.w
             + v4 * wC.y + v5 * wC.w + v6 * wD.y + v7 * wD.w;
    p0 += __shfl_xor(p0, 1); p0 += __shfl_xor(p0, 2);
    p0 += __shfl_xor(p0, 4); p0 += __shfl_xor(p0, 8);
    p1 += __shfl_xor(p1, 1); p1 += __shfl_xor(p1, 2);
    p1 += __shfl_xor(p1, 4); p1 += __shfl_xor(p1, 8);
    if (lane == 0) ((float2*)h2p)[i] = make_float2(p0 * di, p1 * di);
}

// ---- layer-2 aggregate + skip: 16 lanes per node (deg~16.7), 4 nodes/wave ----
__global__ __launch_bounds__(256) void agg2_kernel(const float* __restrict__ h2p,
                                                   const float* __restrict__ dinv,
                                                   const int2* __restrict__ row2,
                                                   const int* __restrict__ col_src,
                                                   const float* __restrict__ skip,
                                                   float* __restrict__ out, int n) {
    const int tid = threadIdx.x;
    const int grp = tid >> 4;       // 16 node-groups per block
    const int el  = tid & 15;
    const int i = blockIdx.x * 16 + grp;
    if (i >= n) return;
    const float di = dinv[i];
    const int2 be = row2[i];
    float a0 = 0.f, a1 = 0.f;
    for (int e = be.x + el; e < be.y; e += 16) {
        int s = col_src[e];
        float2 hs = ((const float2*)h2p)[s];   // pads -> sentinel zeros
        a0 += hs.x;
        a1 += hs.y;
    }
    a0 += __shfl_xor(a0, 1); a0 += __shfl_xor(a0, 2);
    a0 += __shfl_xor(a0, 4); a0 += __shfl_xor(a0, 8);
    a1 += __shfl_xor(a1, 1); a1 += __shfl_xor(a1, 2);
    a1 += __shfl_xor(a1, 4); a1 += __shfl_xor(a1, 8);
    if (el == 0) {
        float2 self = ((const float2*)h2p)[i];
        float2 sk = ((const float2*)skip)[i];
        ((float2*)out)[i] = make_float2(di * (a0 + self.x) + sk.x,
                                        di * (a1 + self.y) + sk.y);
    }
}

extern "C" void kernel_launch(void* const* d_in, const int* in_sizes, int n_in,
                              void* d_out, int out_size, void* d_ws, size_t ws_size,
                              hipStream_t stream) {
    const float* x  = (const float*)d_in[0];
    const int*   ei = (const int*)d_in[1];
    const float* W1 = (const float*)d_in[2];
    const float* b1 = (const float*)d_in[3];
    const float* W2 = (const float*)d_in[4];
    const float* b2 = (const float*)d_in[5];
    const float* Ws = (const float*)d_in[6];
    const float* bs = (const float*)d_in[7];
    float* out = (float*)d_out;

    const int n = in_sizes[0] / IND;        // 100000
    const int E = in_sizes[1] / 2;          // 1600000
    const int NB = (n + 255) >> 8;          // 391 buckets

    char* ws = (char*)d_ws;
    size_t off = 0;
    auto alloc = [&](size_t bytes) { void* p = ws + off; off += (bytes + 255) & ~(size_t)255; return p; };
    int*            flag        = (int*)alloc(256);
    int*            bucket_len  = (int*)alloc((size_t)(MAXNB + 1) * 4);
    unsigned*       slab        = (unsigned*)alloc((size_t)NB * SLAB * 4);
    int2*           row2        = (int2*)alloc((size_t)n * 8);
    float*          dinv        = (float*)alloc((size_t)n * 4);
    int*            col_src     = (int*)alloc((size_t)NB * SLAB * 4);
    unsigned char*  hb8         = (unsigned char*)alloc((size_t)(n + 1) * HID);
    float*          h2p         = (float*)alloc((size_t)(n + 1) * 2 * 4);
    float*          skip        = (float*)alloc((size_t)n * 2 * 4);
    unsigned short* w1t         = (unsigned short*)alloc((size_t)HID * KP * 2);
    (void)ws_size;

    setup_kernel<<<97, 256, 0, stream>>>(W1, w1t, ei, flag, bucket_len, NB);
    partition_kernel<<<(E + 8191) / 8192, 256, 0, stream>>>(ei, flag, bucket_len, slab, E, NB);
    buildb_kernel<<<NB, 256, 0, stream>>>(slab, bucket_len, row2, dinv, col_src, n);

    gemm1_kernel<<<(n + BM - 1) / BM, 256, 0, stream>>>(x, w1t, Ws, bs, b2, dinv, hb8, h2p, skip, n);
    agg1_kernel<<<(n + 3) / 4, 256, 0, stream>>>(hb8, dinv, row2, col_src, b1, W2, h2p, n);
    agg2_kernel<<<(n + 15) / 16, 256, 0, stream>>>(h2p, dinv, row2, col_src, skip, out, n);
}